// Round 4
// baseline (433.897 us; speedup 1.0000x reference)
//
#include <hip/hip_runtime.h>

typedef __attribute__((ext_vector_type(8))) short short8;
typedef __attribute__((ext_vector_type(4))) float f32x4;

__device__ __forceinline__ unsigned short f2bf(float f) {
    unsigned u = __float_as_uint(f);
    u += 0x7FFF + ((u >> 16) & 1);          // round-to-nearest-even
    return (unsigned short)(u >> 16);
}

// ---------------------------------------------------------------------------
// 1) Histogram of edges over dst (N bins)
// ---------------------------------------------------------------------------
__global__ __launch_bounds__(256) void hist_kernel(
    const int* __restrict__ edst, int* __restrict__ counts, int E)
{
    int i = blockIdx.x * 256 + threadIdx.x;
    const int stride = gridDim.x * 256;
    for (; i < E; i += stride)
        atomicAdd(&counts[edst[i]], 1);
}

// ---------------------------------------------------------------------------
// 2) Exclusive prefix scan over counts[NB]  (3 kernels, 1024 items/block)
// ---------------------------------------------------------------------------
__global__ __launch_bounds__(256) void scan1_kernel(
    const int* __restrict__ counts, int* __restrict__ blockSums, int NB)
{
    __shared__ int sd[256];
    const int t = threadIdx.x;
    const int base = blockIdx.x * 1024 + t * 4;
    int s = 0;
#pragma unroll
    for (int i = 0; i < 4; ++i) { int idx = base + i; if (idx < NB) s += counts[idx]; }
    sd[t] = s; __syncthreads();
    for (int off = 128; off > 0; off >>= 1) {
        if (t < off) sd[t] += sd[t + off];
        __syncthreads();
    }
    if (t == 0) blockSums[blockIdx.x] = sd[0];
}

__global__ __launch_bounds__(512) void scan2_kernel(int* blockSums, int nb)
{
    __shared__ int sd[512];
    const int t = threadIdx.x;
    const int v = (t < nb) ? blockSums[t] : 0;
    sd[t] = v; __syncthreads();
    for (int off = 1; off < 512; off <<= 1) {
        int x = (t >= off) ? sd[t - off] : 0;
        __syncthreads();
        sd[t] += x;
        __syncthreads();
    }
    if (t < nb) blockSums[t] = sd[t] - v;   // exclusive
}

__global__ __launch_bounds__(256) void scan3_kernel(
    const int* __restrict__ counts, const int* __restrict__ blockSums,
    int* __restrict__ offsets, int NB)
{
    __shared__ int sd[256];
    const int t = threadIdx.x;
    const int base = blockIdx.x * 1024 + t * 4;
    int c[4]; int s = 0;
#pragma unroll
    for (int i = 0; i < 4; ++i) { int idx = base + i; c[i] = (idx < NB) ? counts[idx] : 0; s += c[i]; }
    sd[t] = s; __syncthreads();
    for (int off = 1; off < 256; off <<= 1) {
        int x = (t >= off) ? sd[t - off] : 0;
        __syncthreads();
        sd[t] += x;
        __syncthreads();
    }
    int run = sd[t] - s + blockSums[blockIdx.x];
#pragma unroll
    for (int i = 0; i < 4; ++i) { int idx = base + i; if (idx < NB) offsets[idx] = run; run += c[i]; }
}

// ---------------------------------------------------------------------------
// 3) Scatter packed (rel<<28)|src into dst-sorted order.
//    Destroys offsets: afterwards offsets[dst] == end of bucket.
// ---------------------------------------------------------------------------
__global__ __launch_bounds__(256) void scatter_fill_kernel(
    const int* __restrict__ esrc, const int* __restrict__ edst,
    const int* __restrict__ erel, int* __restrict__ offsets,
    unsigned* __restrict__ sorted, int E)
{
    int i = blockIdx.x * 256 + threadIdx.x;
    const int stride = gridDim.x * 256;
    for (; i < E; i += stride) {
        const int pos = atomicAdd(&offsets[edst[i]], 1);
        sorted[pos] = (unsigned)esrc[i] | ((unsigned)erel[i] << 28);
    }
}

// ---------------------------------------------------------------------------
// 4) dst-major aggregate: one wave per dst node. All R=8 relation
//    accumulators live in registers (float2 each). Writes the full
//    A[dst][0..1151] row (8 scaled segments + bf16(X[dst]) self segment).
//    No atomics, every A element written exactly once.
// ---------------------------------------------------------------------------
__global__ __launch_bounds__(256) void aggregate_kernel(
    const float* __restrict__ X, const float* __restrict__ inv_norm,
    const unsigned* __restrict__ sorted, const int* __restrict__ counts,
    const int* __restrict__ bucket_end, unsigned short* __restrict__ A,
    int N)
{
    const int dst = (int)((blockIdx.x * blockDim.x + threadIdx.x) >> 6);
    if (dst >= N) return;
    const int lane = threadIdx.x & 63;

    const int end = bucket_end[dst];
    const int start = end - counts[dst];

    float2 acc[8];
#pragma unroll
    for (int r = 0; r < 8; ++r) acc[r] = make_float2(0.f, 0.f);

    int i = start;
    while (i < end) {
        const int take = min(64, end - i);
        const int idx = i + ((lane < take) ? lane : 0);
        const unsigned pvec = sorted[idx];          // coalesced batch of edges

        const int main4 = take & ~3;
        int j = 0;
        for (; j < main4; j += 4) {
            unsigned p0 = (unsigned)__shfl((int)pvec, j);
            unsigned p1 = (unsigned)__shfl((int)pvec, j + 1);
            unsigned p2 = (unsigned)__shfl((int)pvec, j + 2);
            unsigned p3 = (unsigned)__shfl((int)pvec, j + 3);
            const float2 v0 = ((const float2*)(X + ((size_t)(p0 & 0x0FFFFFFFu) << 7)))[lane];
            const float2 v1 = ((const float2*)(X + ((size_t)(p1 & 0x0FFFFFFFu) << 7)))[lane];
            const float2 v2 = ((const float2*)(X + ((size_t)(p2 & 0x0FFFFFFFu) << 7)))[lane];
            const float2 v3 = ((const float2*)(X + ((size_t)(p3 & 0x0FFFFFFFu) << 7)))[lane];
            {   const int r = p0 >> 28; acc[r].x += v0.x; acc[r].y += v0.y; }
            {   const int r = p1 >> 28; acc[r].x += v1.x; acc[r].y += v1.y; }
            {   const int r = p2 >> 28; acc[r].x += v2.x; acc[r].y += v2.y; }
            {   const int r = p3 >> 28; acc[r].x += v3.x; acc[r].y += v3.y; }
        }
        for (; j < take; ++j) {
            unsigned p = (unsigned)__shfl((int)pvec, j);
            const float2 v = ((const float2*)(X + ((size_t)(p & 0x0FFFFFFFu) << 7)))[lane];
            const int r = p >> 28;
            acc[r].x += v.x; acc[r].y += v.y;
        }
        i += take;
    }

    // inv_norm[r*N+dst] for r=0..7: lanes 0..7 fetch, broadcast by shuffle
    const float nv = (lane < 8) ? inv_norm[(size_t)lane * N + dst] : 0.f;

    unsigned short* Arow = A + (size_t)dst * 1152 + lane * 2;
#pragma unroll
    for (int r = 0; r < 8; ++r) {
        const float s = __shfl(nv, r);
        const unsigned packed = (unsigned)f2bf(acc[r].x * s)
                              | ((unsigned)f2bf(acc[r].y * s) << 16);
        *(unsigned*)(Arow + r * 128) = packed;
    }
    // self segment: bf16(X[dst])
    const float2 xv = ((const float2*)(X + ((size_t)dst << 7)))[lane];
    const unsigned px = (unsigned)f2bf(xv.x) | ((unsigned)f2bf(xv.y) << 16);
    *(unsigned*)(Arow + 8 * 128) = px;
}

// ---------------------------------------------------------------------------
// 5) Build Bt[n][k] = [W;W0]^T in bf16.  (X cast fused into aggregate.)
// ---------------------------------------------------------------------------
__global__ __launch_bounds__(256) void castB_kernel(
    const float* __restrict__ W, const float* __restrict__ W0,
    unsigned short* __restrict__ Bt, int R)
{
    const int ktot = (R + 1) * 128;
    const int idx = blockIdx.x * 256 + threadIdx.x;
    if (idx >= 128 * ktot) return;
    const int n = idx / ktot;
    const int k = idx - n * ktot;
    const float v = (k < R * 128) ? W[(size_t)k * 128 + n]
                                  : W0[(size_t)(k - R * 128) * 128 + n];
    Bt[(size_t)n * ktot + k] = f2bf(v);
}

// ---------------------------------------------------------------------------
// 6) bf16 MFMA GEMM, no LDS: out[M,128] = A[M,KT] @ Bt[128,KT]^T (fp32 out)
//    256 threads = 4 waves x 16 rows = 64 rows/block. B fragments stream
//    from L1/L2 (Bt is 294 KB, shared by every block). No __syncthreads.
// ---------------------------------------------------------------------------
template <int KT>
__global__ __launch_bounds__(256) void gemm_kernel(
    const unsigned short* __restrict__ A, const unsigned short* __restrict__ Bt,
    float* __restrict__ out, int M)
{
    const int tid = threadIdx.x;
    const int wave = tid >> 6;
    const int lane = tid & 63;
    const int ln = lane & 15, quad = lane >> 4;
    const int m0 = blockIdx.x * 64 + wave * 16;
    int m = m0 + ln; if (m >= M) m = M - 1;            // clamp; stores guarded
    const unsigned short* Arow = A + (size_t)m * KT + quad * 8;
    const unsigned short* Bbase = Bt + (size_t)ln * KT + quad * 8;

    f32x4 acc[8] = {};
#pragma unroll
    for (int kb = 0; kb < KT / 32; ++kb) {
        const int k0 = kb << 5;
        const short8 a = *(const short8*)(Arow + k0);
#pragma unroll
        for (int c = 0; c < 8; ++c) {
            const short8 b = *(const short8*)(Bbase + (size_t)c * 16 * KT + k0);
            acc[c] = __builtin_amdgcn_mfma_f32_16x16x32_bf16(a, b, acc[c], 0, 0, 0);
        }
    }
#pragma unroll
    for (int c = 0; c < 8; ++c) {
#pragma unroll
        for (int rg = 0; rg < 4; ++rg) {
            const int row = m0 + quad * 4 + rg;
            if (row < M) out[(size_t)row * 128 + c * 16 + ln] = acc[c][rg];
        }
    }
}

// Generic-K fallback (runtime loop bound)
__global__ __launch_bounds__(256) void gemm_kernel_rt(
    const unsigned short* __restrict__ A, const unsigned short* __restrict__ Bt,
    float* __restrict__ out, int M, int ktot)
{
    const int tid = threadIdx.x;
    const int wave = tid >> 6;
    const int lane = tid & 63;
    const int ln = lane & 15, quad = lane >> 4;
    const int m0 = blockIdx.x * 64 + wave * 16;
    int m = m0 + ln; if (m >= M) m = M - 1;
    const unsigned short* Arow = A + (size_t)m * ktot + quad * 8;
    const unsigned short* Bbase = Bt + (size_t)ln * ktot + quad * 8;

    f32x4 acc[8] = {};
    for (int kb = 0; kb < (ktot >> 5); ++kb) {
        const int k0 = kb << 5;
        const short8 a = *(const short8*)(Arow + k0);
#pragma unroll
        for (int c = 0; c < 8; ++c) {
            const short8 b = *(const short8*)(Bbase + (size_t)c * 16 * ktot + k0);
            acc[c] = __builtin_amdgcn_mfma_f32_16x16x32_bf16(a, b, acc[c], 0, 0, 0);
        }
    }
#pragma unroll
    for (int c = 0; c < 8; ++c) {
#pragma unroll
        for (int rg = 0; rg < 4; ++rg) {
            const int row = m0 + quad * 4 + rg;
            if (row < M) out[(size_t)row * 128 + c * 16 + ln] = acc[c][rg];
        }
    }
}

// ---------------------------------------------------------------------------
extern "C" void kernel_launch(void* const* d_in, const int* in_sizes, int n_in,
                              void* d_out, int out_size, void* d_ws, size_t ws_size,
                              hipStream_t stream) {
    const float* X        = (const float*)d_in[0];
    const float* W        = (const float*)d_in[1];
    const float* W0       = (const float*)d_in[2];
    const float* inv_norm = (const float*)d_in[3];
    const int*   esrc     = (const int*)d_in[4];
    const int*   edst     = (const int*)d_in[5];
    const int*   erel     = (const int*)d_in[6];
    float* out = (float*)d_out;

    const int N  = in_sizes[0] / 128;     // 50000
    const int E  = in_sizes[4];           // 800000
    const int R  = in_sizes[3] / N;       // 8
    const int ktot = (R + 1) * 128;       // 1152

    char* ws = (char*)d_ws;
    size_t off = 0;
    auto alloc = [&](size_t bytes) -> char* {
        char* p = ws + off; off = (off + bytes + 255) & ~(size_t)255; return p;
    };
    unsigned short* A         = (unsigned short*)alloc((size_t)N * ktot * 2);   // 115.2 MB
    unsigned short* Bt        = (unsigned short*)alloc((size_t)128 * ktot * 2); // 0.3 MB
    int*            counts    = (int*)alloc((size_t)N * 4);                     // 0.2 MB
    int*            offsets   = (int*)alloc((size_t)N * 4);                     // 0.2 MB
    int*            blockSums = (int*)alloc(512 * 4);
    unsigned*       sorted    = (unsigned*)alloc((size_t)E * 4);                // 3.2 MB
    (void)ws_size;

    const int nScanBlocks = (N + 1023) / 1024;   // 49 (<=512)

    hipMemsetAsync(counts, 0, (size_t)N * 4, stream);
    hist_kernel<<<1024, 256, 0, stream>>>(edst, counts, E);
    scan1_kernel<<<nScanBlocks, 256, 0, stream>>>(counts, blockSums, N);
    scan2_kernel<<<1, 512, 0, stream>>>(blockSums, nScanBlocks);
    scan3_kernel<<<nScanBlocks, 256, 0, stream>>>(counts, blockSums, offsets, N);
    scatter_fill_kernel<<<1024, 256, 0, stream>>>(esrc, edst, erel, offsets, sorted, E);
    aggregate_kernel<<<(N + 3) / 4, 256, 0, stream>>>(X, inv_norm, sorted, counts, offsets, A, N);
    castB_kernel<<<(128 * ktot + 255) / 256, 256, 0, stream>>>(W, W0, Bt, R);
    if (ktot == 1152)
        gemm_kernel<1152><<<(N + 63) / 64, 256, 0, stream>>>(A, Bt, out, N);
    else
        gemm_kernel_rt<<<(N + 63) / 64, 256, 0, stream>>>(A, Bt, out, N, ktot);
}

// Round 5
// 350.306 us; speedup vs baseline: 1.2386x; 1.2386x over previous
//
#include <hip/hip_runtime.h>

typedef __attribute__((ext_vector_type(8))) short short8;
typedef __attribute__((ext_vector_type(4))) float f32x4;

__device__ __forceinline__ unsigned short f2bf(float f) {
    unsigned u = __float_as_uint(f);
    u += 0x7FFF + ((u >> 16) & 1);          // round-to-nearest-even
    return (unsigned short)(u >> 16);
}

// ---------------------------------------------------------------------------
// 1) Histogram of edges over dst (N bins)
// ---------------------------------------------------------------------------
__global__ __launch_bounds__(256) void hist_kernel(
    const int* __restrict__ edst, int* __restrict__ counts, int E)
{
    int i = blockIdx.x * 256 + threadIdx.x;
    const int stride = gridDim.x * 256;
    for (; i < E; i += stride)
        atomicAdd(&counts[edst[i]], 1);
}

// ---------------------------------------------------------------------------
// 2) Exclusive prefix scan over counts[NB]  (3 kernels, 1024 items/block)
// ---------------------------------------------------------------------------
__global__ __launch_bounds__(256) void scan1_kernel(
    const int* __restrict__ counts, int* __restrict__ blockSums, int NB)
{
    __shared__ int sd[256];
    const int t = threadIdx.x;
    const int base = blockIdx.x * 1024 + t * 4;
    int s = 0;
#pragma unroll
    for (int i = 0; i < 4; ++i) { int idx = base + i; if (idx < NB) s += counts[idx]; }
    sd[t] = s; __syncthreads();
    for (int off = 128; off > 0; off >>= 1) {
        if (t < off) sd[t] += sd[t + off];
        __syncthreads();
    }
    if (t == 0) blockSums[blockIdx.x] = sd[0];
}

__global__ __launch_bounds__(512) void scan2_kernel(int* blockSums, int nb)
{
    __shared__ int sd[512];
    const int t = threadIdx.x;
    const int v = (t < nb) ? blockSums[t] : 0;
    sd[t] = v; __syncthreads();
    for (int off = 1; off < 512; off <<= 1) {
        int x = (t >= off) ? sd[t - off] : 0;
        __syncthreads();
        sd[t] += x;
        __syncthreads();
    }
    if (t < nb) blockSums[t] = sd[t] - v;   // exclusive
}

__global__ __launch_bounds__(256) void scan3_kernel(
    const int* __restrict__ counts, const int* __restrict__ blockSums,
    int* __restrict__ offsets, int NB)
{
    __shared__ int sd[256];
    const int t = threadIdx.x;
    const int base = blockIdx.x * 1024 + t * 4;
    int c[4]; int s = 0;
#pragma unroll
    for (int i = 0; i < 4; ++i) { int idx = base + i; c[i] = (idx < NB) ? counts[idx] : 0; s += c[i]; }
    sd[t] = s; __syncthreads();
    for (int off = 1; off < 256; off <<= 1) {
        int x = (t >= off) ? sd[t - off] : 0;
        __syncthreads();
        sd[t] += x;
        __syncthreads();
    }
    int run = sd[t] - s + blockSums[blockIdx.x];
#pragma unroll
    for (int i = 0; i < 4; ++i) { int idx = base + i; if (idx < NB) offsets[idx] = run; run += c[i]; }
}

// ---------------------------------------------------------------------------
// 3) Scatter packed (rel<<28)|src into dst-sorted order.
//    Destroys offsets: afterwards offsets[dst] == end of bucket.
// ---------------------------------------------------------------------------
__global__ __launch_bounds__(256) void scatter_fill_kernel(
    const int* __restrict__ esrc, const int* __restrict__ edst,
    const int* __restrict__ erel, int* __restrict__ offsets,
    unsigned* __restrict__ sorted, int E)
{
    int i = blockIdx.x * 256 + threadIdx.x;
    const int stride = gridDim.x * 256;
    for (; i < E; i += stride) {
        const int pos = atomicAdd(&offsets[edst[i]], 1);
        sorted[pos] = (unsigned)esrc[i] | ((unsigned)erel[i] << 28);
    }
}

// ---------------------------------------------------------------------------
// 4) dst-major aggregate: one wave per dst node. All R=8 relation
//    accumulators live in registers (float2 each). Writes the full
//    A[dst][0..1151] row (8 scaled segments + bf16(X[dst]) self segment).
//    No atomics, every A element written exactly once.
// ---------------------------------------------------------------------------
__global__ __launch_bounds__(256) void aggregate_kernel(
    const float* __restrict__ X, const float* __restrict__ inv_norm,
    const unsigned* __restrict__ sorted, const int* __restrict__ counts,
    const int* __restrict__ bucket_end, unsigned short* __restrict__ A,
    int N)
{
    const int dst = (int)((blockIdx.x * blockDim.x + threadIdx.x) >> 6);
    if (dst >= N) return;
    const int lane = threadIdx.x & 63;

    const int end = bucket_end[dst];
    const int start = end - counts[dst];

    float2 acc[8];
#pragma unroll
    for (int r = 0; r < 8; ++r) acc[r] = make_float2(0.f, 0.f);

    int i = start;
    while (i < end) {
        const int take = min(64, end - i);
        const int idx = i + ((lane < take) ? lane : 0);
        const unsigned pvec = sorted[idx];          // coalesced batch of edges

        const int main4 = take & ~3;
        int j = 0;
        for (; j < main4; j += 4) {
            unsigned p0 = (unsigned)__shfl((int)pvec, j);
            unsigned p1 = (unsigned)__shfl((int)pvec, j + 1);
            unsigned p2 = (unsigned)__shfl((int)pvec, j + 2);
            unsigned p3 = (unsigned)__shfl((int)pvec, j + 3);
            const float2 v0 = ((const float2*)(X + ((size_t)(p0 & 0x0FFFFFFFu) << 7)))[lane];
            const float2 v1 = ((const float2*)(X + ((size_t)(p1 & 0x0FFFFFFFu) << 7)))[lane];
            const float2 v2 = ((const float2*)(X + ((size_t)(p2 & 0x0FFFFFFFu) << 7)))[lane];
            const float2 v3 = ((const float2*)(X + ((size_t)(p3 & 0x0FFFFFFFu) << 7)))[lane];
            {   const int r = p0 >> 28; acc[r].x += v0.x; acc[r].y += v0.y; }
            {   const int r = p1 >> 28; acc[r].x += v1.x; acc[r].y += v1.y; }
            {   const int r = p2 >> 28; acc[r].x += v2.x; acc[r].y += v2.y; }
            {   const int r = p3 >> 28; acc[r].x += v3.x; acc[r].y += v3.y; }
        }
        for (; j < take; ++j) {
            unsigned p = (unsigned)__shfl((int)pvec, j);
            const float2 v = ((const float2*)(X + ((size_t)(p & 0x0FFFFFFFu) << 7)))[lane];
            const int r = p >> 28;
            acc[r].x += v.x; acc[r].y += v.y;
        }
        i += take;
    }

    // inv_norm[r*N+dst] for r=0..7: lanes 0..7 fetch, broadcast by shuffle
    const float nv = (lane < 8) ? inv_norm[(size_t)lane * N + dst] : 0.f;

    unsigned short* Arow = A + (size_t)dst * 1152 + lane * 2;
#pragma unroll
    for (int r = 0; r < 8; ++r) {
        const float s = __shfl(nv, r);
        const unsigned packed = (unsigned)f2bf(acc[r].x * s)
                              | ((unsigned)f2bf(acc[r].y * s) << 16);
        *(unsigned*)(Arow + r * 128) = packed;
    }
    // self segment: bf16(X[dst])
    const float2 xv = ((const float2*)(X + ((size_t)dst << 7)))[lane];
    const unsigned px = (unsigned)f2bf(xv.x) | ((unsigned)f2bf(xv.y) << 16);
    *(unsigned*)(Arow + 8 * 128) = px;
}

// ---------------------------------------------------------------------------
// 5) Build Bt[n][k] = [W;W0]^T in bf16.  (X cast fused into aggregate.)
// ---------------------------------------------------------------------------
__global__ __launch_bounds__(256) void castB_kernel(
    const float* __restrict__ W, const float* __restrict__ W0,
    unsigned short* __restrict__ Bt, int R)
{
    const int ktot = (R + 1) * 128;
    const int idx = blockIdx.x * 256 + threadIdx.x;
    if (idx >= 128 * ktot) return;
    const int n = idx / ktot;
    const int k = idx - n * ktot;
    const float v = (k < R * 128) ? W[(size_t)k * 128 + n]
                                  : W0[(size_t)(k - R * 128) * 128 + n];
    Bt[(size_t)n * ktot + k] = f2bf(v);
}

// ---------------------------------------------------------------------------
// 6) bf16 MFMA GEMM: out[M,128] = A[M,KT] @ Bt[128,KT]^T (fp32 out)
//    512 threads = 8 waves. Block: 64 rows x 128 cols. Wave w: m-tile
//    (w>>1), col-half (w&1) -> 4 c-tiles, acc = 16 VGPRs. B tile (32k x
//    128n) staged in LDS each k-step by all 512 threads (16B each);
//    A fragments direct from global (coalesced 64B row segments).
// ---------------------------------------------------------------------------
template <int KT>
__global__ __launch_bounds__(512) void gemm_kernel(
    const unsigned short* __restrict__ A, const unsigned short* __restrict__ Bt,
    float* __restrict__ out, int M)
{
    __shared__ unsigned short Bs[128][40];   // [n][32k] + 8 pad (80B pitch)
    const int tid = threadIdx.x;
    const int wave = tid >> 6;               // 0..7
    const int lane = tid & 63;
    const int ln = lane & 15, quad = lane >> 4;
    const int mt = wave >> 1;                // 0..3 (16-row tile)
    const int half = wave & 1;               // 0..1 (64-col half)
    const int m0 = blockIdx.x * 64;
    int m = m0 + mt * 16 + ln; if (m >= M) m = M - 1;   // clamp; stores guarded
    const unsigned short* Arow = A + (size_t)m * KT + quad * 8;

    // B staging: thread t stages 16B chunk t: n = t>>2, kk = t&3
    const int sn = tid >> 2, skk = tid & 3;
    const unsigned short* Bsrc = Bt + (size_t)sn * KT + skk * 8;

    f32x4 acc[4] = {};
    for (int kb = 0; kb < KT / 32; ++kb) {
        const int k0 = kb << 5;
        const short8 bstage = *(const short8*)(Bsrc + k0);   // L2-hot (Bt=294KB)
        const short8 a = *(const short8*)(Arow + k0);        // streaming
        __syncthreads();
        *(short8*)&Bs[sn][skk * 8] = bstage;
        __syncthreads();
#pragma unroll
        for (int c = 0; c < 4; ++c) {
            const short8 b = *(const short8*)&Bs[half * 64 + c * 16 + ln][quad * 8];
            acc[c] = __builtin_amdgcn_mfma_f32_16x16x32_bf16(a, b, acc[c], 0, 0, 0);
        }
    }
#pragma unroll
    for (int c = 0; c < 4; ++c) {
#pragma unroll
        for (int rg = 0; rg < 4; ++rg) {
            const int row = m0 + mt * 16 + quad * 4 + rg;
            if (row < M)
                out[(size_t)row * 128 + half * 64 + c * 16 + ln] = acc[c][rg];
        }
    }
}

// Generic-K fallback (runtime loop bound), slow but correct
__global__ __launch_bounds__(256) void gemm_kernel_rt(
    const unsigned short* __restrict__ A, const unsigned short* __restrict__ Bt,
    float* __restrict__ out, int M, int ktot)
{
    const int tid = threadIdx.x;
    const int wave = tid >> 6;
    const int lane = tid & 63;
    const int ln = lane & 15, quad = lane >> 4;
    const int m0 = blockIdx.x * 64 + wave * 16;
    int m = m0 + ln; if (m >= M) m = M - 1;
    const unsigned short* Arow = A + (size_t)m * ktot + quad * 8;
    const unsigned short* Bbase = Bt + (size_t)ln * ktot + quad * 8;

    f32x4 acc[8] = {};
    for (int kb = 0; kb < (ktot >> 5); ++kb) {
        const int k0 = kb << 5;
        const short8 a = *(const short8*)(Arow + k0);
#pragma unroll
        for (int c = 0; c < 8; ++c) {
            const short8 b = *(const short8*)(Bbase + (size_t)c * 16 * ktot + k0);
            acc[c] = __builtin_amdgcn_mfma_f32_16x16x32_bf16(a, b, acc[c], 0, 0, 0);
        }
    }
#pragma unroll
    for (int c = 0; c < 8; ++c) {
#pragma unroll
        for (int rg = 0; rg < 4; ++rg) {
            const int row = m0 + quad * 4 + rg;
            if (row < M) out[(size_t)row * 128 + c * 16 + ln] = acc[c][rg];
        }
    }
}

// ---------------------------------------------------------------------------
extern "C" void kernel_launch(void* const* d_in, const int* in_sizes, int n_in,
                              void* d_out, int out_size, void* d_ws, size_t ws_size,
                              hipStream_t stream) {
    const float* X        = (const float*)d_in[0];
    const float* W        = (const float*)d_in[1];
    const float* W0       = (const float*)d_in[2];
    const float* inv_norm = (const float*)d_in[3];
    const int*   esrc     = (const int*)d_in[4];
    const int*   edst     = (const int*)d_in[5];
    const int*   erel     = (const int*)d_in[6];
    float* out = (float*)d_out;

    const int N  = in_sizes[0] / 128;     // 50000
    const int E  = in_sizes[4];           // 800000
    const int R  = in_sizes[3] / N;       // 8
    const int ktot = (R + 1) * 128;       // 1152

    char* ws = (char*)d_ws;
    size_t off = 0;
    auto alloc = [&](size_t bytes) -> char* {
        char* p = ws + off; off = (off + bytes + 255) & ~(size_t)255; return p;
    };
    unsigned short* A         = (unsigned short*)alloc((size_t)N * ktot * 2);   // 115.2 MB
    unsigned short* Bt        = (unsigned short*)alloc((size_t)128 * ktot * 2); // 0.3 MB
    int*            counts    = (int*)alloc((size_t)N * 4);                     // 0.2 MB
    int*            offsets   = (int*)alloc((size_t)N * 4);                     // 0.2 MB
    int*            blockSums = (int*)alloc(512 * 4);
    unsigned*       sorted    = (unsigned*)alloc((size_t)E * 4);                // 3.2 MB
    (void)ws_size;

    const int nScanBlocks = (N + 1023) / 1024;   // 49 (<=512)

    hipMemsetAsync(counts, 0, (size_t)N * 4, stream);
    hist_kernel<<<1024, 256, 0, stream>>>(edst, counts, E);
    scan1_kernel<<<nScanBlocks, 256, 0, stream>>>(counts, blockSums, N);
    scan2_kernel<<<1, 512, 0, stream>>>(blockSums, nScanBlocks);
    scan3_kernel<<<nScanBlocks, 256, 0, stream>>>(counts, blockSums, offsets, N);
    scatter_fill_kernel<<<1024, 256, 0, stream>>>(esrc, edst, erel, offsets, sorted, E);
    aggregate_kernel<<<(N + 3) / 4, 256, 0, stream>>>(X, inv_norm, sorted, counts, offsets, A, N);
    castB_kernel<<<(128 * ktot + 255) / 256, 256, 0, stream>>>(W, W0, Bt, R);
    if (ktot == 1152)
        gemm_kernel<1152><<<(N + 63) / 64, 512, 0, stream>>>(A, Bt, out, N);
    else
        gemm_kernel_rt<<<(N + 63) / 64, 256, 0, stream>>>(A, Bt, out, N, ktot);
}

// Round 6
// 296.997 us; speedup vs baseline: 1.4609x; 1.1795x over previous
//
#include <hip/hip_runtime.h>

typedef __attribute__((ext_vector_type(8))) short short8;
typedef __attribute__((ext_vector_type(4))) float f32x4;

__device__ __forceinline__ unsigned short f2bf(float f) {
    unsigned u = __float_as_uint(f);
    u += 0x7FFF + ((u >> 16) & 1);          // round-to-nearest-even
    return (unsigned short)(u >> 16);
}

__device__ __forceinline__ float readlane_f(float v, int l) {
    return __int_as_float(__builtin_amdgcn_readlane(__float_as_int(v), l));
}

// ---------------------------------------------------------------------------
// 1) Histogram of edges over key = dst*8 + rel  (8N bins)
// ---------------------------------------------------------------------------
__global__ __launch_bounds__(256) void hist_kernel(
    const int* __restrict__ edst, const int* __restrict__ erel,
    int* __restrict__ counts, int E)
{
    int i = blockIdx.x * 256 + threadIdx.x;
    const int stride = gridDim.x * 256;
    for (; i < E; i += stride)
        atomicAdd(&counts[edst[i] * 8 + erel[i]], 1);
}

// ---------------------------------------------------------------------------
// 2) Exclusive prefix scan over counts[KB]  (3 kernels, 1024 items/block)
// ---------------------------------------------------------------------------
__global__ __launch_bounds__(256) void scan1_kernel(
    const int* __restrict__ counts, int* __restrict__ blockSums, int KB)
{
    __shared__ int sd[256];
    const int t = threadIdx.x;
    const int base = blockIdx.x * 1024 + t * 4;
    int s = 0;
#pragma unroll
    for (int i = 0; i < 4; ++i) { int idx = base + i; if (idx < KB) s += counts[idx]; }
    sd[t] = s; __syncthreads();
    for (int off = 128; off > 0; off >>= 1) {
        if (t < off) sd[t] += sd[t + off];
        __syncthreads();
    }
    if (t == 0) blockSums[blockIdx.x] = sd[0];
}

__global__ __launch_bounds__(512) void scan2_kernel(int* blockSums, int nb)
{
    __shared__ int sd[512];
    const int t = threadIdx.x;
    const int v = (t < nb) ? blockSums[t] : 0;
    sd[t] = v; __syncthreads();
    for (int off = 1; off < 512; off <<= 1) {
        int x = (t >= off) ? sd[t - off] : 0;
        __syncthreads();
        sd[t] += x;
        __syncthreads();
    }
    if (t < nb) blockSums[t] = sd[t] - v;   // exclusive
}

__global__ __launch_bounds__(256) void scan3_kernel(
    const int* __restrict__ counts, const int* __restrict__ blockSums,
    int* __restrict__ offsets, int KB)
{
    __shared__ int sd[256];
    const int t = threadIdx.x;
    const int base = blockIdx.x * 1024 + t * 4;
    int c[4]; int s = 0;
#pragma unroll
    for (int i = 0; i < 4; ++i) { int idx = base + i; c[i] = (idx < KB) ? counts[idx] : 0; s += c[i]; }
    sd[t] = s; __syncthreads();
    for (int off = 1; off < 256; off <<= 1) {
        int x = (t >= off) ? sd[t - off] : 0;
        __syncthreads();
        sd[t] += x;
        __syncthreads();
    }
    int run = sd[t] - s + blockSums[blockIdx.x];
#pragma unroll
    for (int i = 0; i < 4; ++i) { int idx = base + i; if (idx < KB) offsets[idx] = run; run += c[i]; }
}

// ---------------------------------------------------------------------------
// 3) Scatter src into (dst,rel)-sorted order.
//    Destroys offsets: afterwards offsets[key] == end of bucket.
// ---------------------------------------------------------------------------
__global__ __launch_bounds__(256) void scatter_fill_kernel(
    const int* __restrict__ esrc, const int* __restrict__ edst,
    const int* __restrict__ erel, int* __restrict__ offsets,
    int* __restrict__ sorted, int E)
{
    int i = blockIdx.x * 256 + threadIdx.x;
    const int stride = gridDim.x * 256;
    for (; i < E; i += stride) {
        const int pos = atomicAdd(&offsets[edst[i] * 8 + erel[i]], 1);
        sorted[pos] = esrc[i];
    }
}

// ---------------------------------------------------------------------------
// 4) dst-major aggregate, one wave per dst. The 8 relation runs of a dst
//    are contiguous in `sorted`; r is a compile-time unrolled loop var so
//    accumulators are plain scalar VGPRs (NO dynamic indexing -> no LDS
//    demotion, no bank conflicts, no ds_bpermute). Edge srcs broadcast via
//    v_readlane (SGPR) -> X-row gather uses a scalar base address.
// ---------------------------------------------------------------------------
__global__ __launch_bounds__(256) void aggregate_kernel(
    const float* __restrict__ X, const float* __restrict__ inv_norm,
    const int* __restrict__ sorted, const int* __restrict__ counts,
    const int* __restrict__ bucket_end, unsigned short* __restrict__ A,
    int N)
{
    const int dst = (int)((blockIdx.x * blockDim.x + threadIdx.x) >> 6);
    if (dst >= N) return;
    const int lane = threadIdx.x & 63;
    const int key0 = dst * 8;

    const int   cnt_l = (lane < 8) ? counts[key0 + lane] : 0;
    const int   end_l = (lane < 8) ? bucket_end[key0 + lane] : 0;
    const float nv_l  = (lane < 8) ? inv_norm[(size_t)lane * N + dst] : 0.f;

    const int bstart = __builtin_amdgcn_readlane(end_l, 0)
                     - __builtin_amdgcn_readlane(cnt_l, 0);
    const int bend   = __builtin_amdgcn_readlane(end_l, 7);
    const int total  = bend - bstart;

    // one coalesced batch covers the whole bucket in the common case
    int batch = 0;
    if (bstart + lane < bend) batch = sorted[bstart + lane];

    unsigned short* Arow = A + (size_t)dst * 1152 + lane * 2;

#pragma unroll
    for (int r = 0; r < 8; ++r) {
        const int cnt = __builtin_amdgcn_readlane(cnt_l, r);
        const int end = __builtin_amdgcn_readlane(end_l, r);
        const int st  = end - cnt;
        float ax = 0.f, ay = 0.f;
        if (total <= 64) {
            const int base = st - bstart;
            int j = 0;
            for (; j + 4 <= cnt; j += 4) {
                const int s0 = __builtin_amdgcn_readlane(batch, base + j);
                const int s1 = __builtin_amdgcn_readlane(batch, base + j + 1);
                const int s2 = __builtin_amdgcn_readlane(batch, base + j + 2);
                const int s3 = __builtin_amdgcn_readlane(batch, base + j + 3);
                const float2 v0 = ((const float2*)(X + ((size_t)s0 << 7)))[lane];
                const float2 v1 = ((const float2*)(X + ((size_t)s1 << 7)))[lane];
                const float2 v2 = ((const float2*)(X + ((size_t)s2 << 7)))[lane];
                const float2 v3 = ((const float2*)(X + ((size_t)s3 << 7)))[lane];
                ax += v0.x; ay += v0.y;
                ax += v1.x; ay += v1.y;
                ax += v2.x; ay += v2.y;
                ax += v3.x; ay += v3.y;
            }
            for (; j < cnt; ++j) {
                const int s0 = __builtin_amdgcn_readlane(batch, base + j);
                const float2 v = ((const float2*)(X + ((size_t)s0 << 7)))[lane];
                ax += v.x; ay += v.y;
            }
        } else {
            // rare (degree>64): uniform per-edge loads
            int i = st;
            for (; i + 2 <= end; i += 2) {
                const int s0 = sorted[i], s1 = sorted[i + 1];
                const float2 v0 = ((const float2*)(X + ((size_t)s0 << 7)))[lane];
                const float2 v1 = ((const float2*)(X + ((size_t)s1 << 7)))[lane];
                ax += v0.x; ay += v0.y;
                ax += v1.x; ay += v1.y;
            }
            for (; i < end; ++i) {
                const int s0 = sorted[i];
                const float2 v = ((const float2*)(X + ((size_t)s0 << 7)))[lane];
                ax += v.x; ay += v.y;
            }
        }
        const float s = readlane_f(nv_l, r);
        const unsigned packed = (unsigned)f2bf(ax * s)
                              | ((unsigned)f2bf(ay * s) << 16);
        *(unsigned*)(Arow + r * 128) = packed;
    }
    // self segment: bf16(X[dst])
    const float2 xv = ((const float2*)(X + ((size_t)dst << 7)))[lane];
    const unsigned px = (unsigned)f2bf(xv.x) | ((unsigned)f2bf(xv.y) << 16);
    *(unsigned*)(Arow + 8 * 128) = px;
}

// ---------------------------------------------------------------------------
// 5) Build Bt[n][k] = [W;W0]^T in bf16.
// ---------------------------------------------------------------------------
__global__ __launch_bounds__(256) void castB_kernel(
    const float* __restrict__ W, const float* __restrict__ W0,
    unsigned short* __restrict__ Bt, int R)
{
    const int ktot = (R + 1) * 128;
    const int idx = blockIdx.x * 256 + threadIdx.x;
    if (idx >= 128 * ktot) return;
    const int n = idx / ktot;
    const int k = idx - n * ktot;
    const float v = (k < R * 128) ? W[(size_t)k * 128 + n]
                                  : W0[(size_t)(k - R * 128) * 128 + n];
    Bt[(size_t)n * ktot + k] = f2bf(v);
}

// ---------------------------------------------------------------------------
// 6) bf16 MFMA GEMM: out[M,128] = A[M,KT] @ Bt[128,KT]^T (fp32 out)
//    512 threads = 8 waves; 64 rows x 128 cols per block; B staged in LDS.
// ---------------------------------------------------------------------------
template <int KT>
__global__ __launch_bounds__(512) void gemm_kernel(
    const unsigned short* __restrict__ A, const unsigned short* __restrict__ Bt,
    float* __restrict__ out, int M)
{
    __shared__ unsigned short Bs[128][40];   // [n][32k] + 8 pad (80B pitch)
    const int tid = threadIdx.x;
    const int wave = tid >> 6;               // 0..7
    const int lane = tid & 63;
    const int ln = lane & 15, quad = lane >> 4;
    const int mt = wave >> 1;                // 0..3 (16-row tile)
    const int half = wave & 1;               // 0..1 (64-col half)
    const int m0 = blockIdx.x * 64;
    int m = m0 + mt * 16 + ln; if (m >= M) m = M - 1;   // clamp; stores guarded
    const unsigned short* Arow = A + (size_t)m * KT + quad * 8;

    const int sn = tid >> 2, skk = tid & 3;
    const unsigned short* Bsrc = Bt + (size_t)sn * KT + skk * 8;

    f32x4 acc[4] = {};
    for (int kb = 0; kb < KT / 32; ++kb) {
        const int k0 = kb << 5;
        const short8 bstage = *(const short8*)(Bsrc + k0);   // L2-hot (Bt=294KB)
        const short8 a = *(const short8*)(Arow + k0);        // streaming
        __syncthreads();
        *(short8*)&Bs[sn][skk * 8] = bstage;
        __syncthreads();
#pragma unroll
        for (int c = 0; c < 4; ++c) {
            const short8 b = *(const short8*)&Bs[half * 64 + c * 16 + ln][quad * 8];
            acc[c] = __builtin_amdgcn_mfma_f32_16x16x32_bf16(a, b, acc[c], 0, 0, 0);
        }
    }
#pragma unroll
    for (int c = 0; c < 4; ++c) {
#pragma unroll
        for (int rg = 0; rg < 4; ++rg) {
            const int row = m0 + mt * 16 + quad * 4 + rg;
            if (row < M)
                out[(size_t)row * 128 + half * 64 + c * 16 + ln] = acc[c][rg];
        }
    }
}

// Generic-K fallback (runtime loop bound), slow but correct
__global__ __launch_bounds__(256) void gemm_kernel_rt(
    const unsigned short* __restrict__ A, const unsigned short* __restrict__ Bt,
    float* __restrict__ out, int M, int ktot)
{
    const int tid = threadIdx.x;
    const int wave = tid >> 6;
    const int lane = tid & 63;
    const int ln = lane & 15, quad = lane >> 4;
    const int m0 = blockIdx.x * 64 + wave * 16;
    int m = m0 + ln; if (m >= M) m = M - 1;
    const unsigned short* Arow = A + (size_t)m * ktot + quad * 8;
    const unsigned short* Bbase = Bt + (size_t)ln * ktot + quad * 8;

    f32x4 acc[8] = {};
    for (int kb = 0; kb < (ktot >> 5); ++kb) {
        const int k0 = kb << 5;
        const short8 a = *(const short8*)(Arow + k0);
#pragma unroll
        for (int c = 0; c < 8; ++c) {
            const short8 b = *(const short8*)(Bbase + (size_t)c * 16 * ktot + k0);
            acc[c] = __builtin_amdgcn_mfma_f32_16x16x32_bf16(a, b, acc[c], 0, 0, 0);
        }
    }
#pragma unroll
    for (int c = 0; c < 8; ++c) {
#pragma unroll
        for (int rg = 0; rg < 4; ++rg) {
            const int row = m0 + quad * 4 + rg;
            if (row < M) out[(size_t)row * 128 + c * 16 + ln] = acc[c][rg];
        }
    }
}

// ---------------------------------------------------------------------------
extern "C" void kernel_launch(void* const* d_in, const int* in_sizes, int n_in,
                              void* d_out, int out_size, void* d_ws, size_t ws_size,
                              hipStream_t stream) {
    const float* X        = (const float*)d_in[0];
    const float* W        = (const float*)d_in[1];
    const float* W0       = (const float*)d_in[2];
    const float* inv_norm = (const float*)d_in[3];
    const int*   esrc     = (const int*)d_in[4];
    const int*   edst     = (const int*)d_in[5];
    const int*   erel     = (const int*)d_in[6];
    float* out = (float*)d_out;

    const int N  = in_sizes[0] / 128;     // 50000
    const int E  = in_sizes[4];           // 800000
    const int R  = in_sizes[3] / N;       // 8
    const int KB = N * 8;                 // 400000 (dst-major keys)
    const int ktot = (R + 1) * 128;       // 1152

    char* ws = (char*)d_ws;
    size_t off = 0;
    auto alloc = [&](size_t bytes) -> char* {
        char* p = ws + off; off = (off + bytes + 255) & ~(size_t)255; return p;
    };
    unsigned short* A         = (unsigned short*)alloc((size_t)N * ktot * 2);   // 115.2 MB
    unsigned short* Bt        = (unsigned short*)alloc((size_t)128 * ktot * 2); // 0.3 MB
    int*            counts    = (int*)alloc((size_t)KB * 4);                    // 1.6 MB
    int*            offsets   = (int*)alloc((size_t)KB * 4);                    // 1.6 MB
    int*            blockSums = (int*)alloc(512 * 4);
    int*            sorted    = (int*)alloc((size_t)E * 4);                     // 3.2 MB
    (void)ws_size;

    const int nScanBlocks = (KB + 1023) / 1024;   // 391 (<=512)

    hipMemsetAsync(counts, 0, (size_t)KB * 4, stream);
    hist_kernel<<<1024, 256, 0, stream>>>(edst, erel, counts, E);
    scan1_kernel<<<nScanBlocks, 256, 0, stream>>>(counts, blockSums, KB);
    scan2_kernel<<<1, 512, 0, stream>>>(blockSums, nScanBlocks);
    scan3_kernel<<<nScanBlocks, 256, 0, stream>>>(counts, blockSums, offsets, KB);
    scatter_fill_kernel<<<1024, 256, 0, stream>>>(esrc, edst, erel, offsets, sorted, E);
    aggregate_kernel<<<(N + 3) / 4, 256, 0, stream>>>(X, inv_norm, sorted, counts, offsets, A, N);
    castB_kernel<<<(128 * ktot + 255) / 256, 256, 0, stream>>>(W, W0, Bt, R);
    if (ktot == 1152)
        gemm_kernel<1152><<<(N + 63) / 64, 512, 0, stream>>>(A, Bt, out, N);
    else
        gemm_kernel_rt<<<(N + 63) / 64, 256, 0, stream>>>(A, Bt, out, N, ktot);
}

// Round 7
// 286.594 us; speedup vs baseline: 1.5140x; 1.0363x over previous
//
#include <hip/hip_runtime.h>

typedef __attribute__((ext_vector_type(8))) short short8;
typedef __attribute__((ext_vector_type(4))) float f32x4;

__device__ __forceinline__ unsigned short f2bf(float f) {
    unsigned u = __float_as_uint(f);
    u += 0x7FFF + ((u >> 16) & 1);          // round-to-nearest-even
    return (unsigned short)(u >> 16);
}

__device__ __forceinline__ float readlane_f(float v, int l) {
    return __int_as_float(__builtin_amdgcn_readlane(__float_as_int(v), l));
}

__device__ __forceinline__ float bflo(unsigned u) { return __uint_as_float(u << 16); }
__device__ __forceinline__ float bfhi(unsigned u) { return __uint_as_float(u & 0xFFFF0000u); }

// ---------------------------------------------------------------------------
// 1) Histogram of edges over key = dst*8 + rel  (8N bins)
// ---------------------------------------------------------------------------
__global__ __launch_bounds__(256) void hist_kernel(
    const int* __restrict__ edst, const int* __restrict__ erel,
    int* __restrict__ counts, int E)
{
    int i = blockIdx.x * 256 + threadIdx.x;
    const int stride = gridDim.x * 256;
    for (; i < E; i += stride)
        atomicAdd(&counts[edst[i] * 8 + erel[i]], 1);
}

// ---------------------------------------------------------------------------
// 2) Exclusive prefix scan over counts[KB]  (3 kernels, 1024 items/block)
// ---------------------------------------------------------------------------
__global__ __launch_bounds__(256) void scan1_kernel(
    const int* __restrict__ counts, int* __restrict__ blockSums, int KB)
{
    __shared__ int sd[256];
    const int t = threadIdx.x;
    const int base = blockIdx.x * 1024 + t * 4;
    int s = 0;
#pragma unroll
    for (int i = 0; i < 4; ++i) { int idx = base + i; if (idx < KB) s += counts[idx]; }
    sd[t] = s; __syncthreads();
    for (int off = 128; off > 0; off >>= 1) {
        if (t < off) sd[t] += sd[t + off];
        __syncthreads();
    }
    if (t == 0) blockSums[blockIdx.x] = sd[0];
}

__global__ __launch_bounds__(512) void scan2_kernel(int* blockSums, int nb)
{
    __shared__ int sd[512];
    const int t = threadIdx.x;
    const int v = (t < nb) ? blockSums[t] : 0;
    sd[t] = v; __syncthreads();
    for (int off = 1; off < 512; off <<= 1) {
        int x = (t >= off) ? sd[t - off] : 0;
        __syncthreads();
        sd[t] += x;
        __syncthreads();
    }
    if (t < nb) blockSums[t] = sd[t] - v;   // exclusive
}

__global__ __launch_bounds__(256) void scan3_kernel(
    const int* __restrict__ counts, const int* __restrict__ blockSums,
    int* __restrict__ offsets, int KB)
{
    __shared__ int sd[256];
    const int t = threadIdx.x;
    const int base = blockIdx.x * 1024 + t * 4;
    int c[4]; int s = 0;
#pragma unroll
    for (int i = 0; i < 4; ++i) { int idx = base + i; c[i] = (idx < KB) ? counts[idx] : 0; s += c[i]; }
    sd[t] = s; __syncthreads();
    for (int off = 1; off < 256; off <<= 1) {
        int x = (t >= off) ? sd[t - off] : 0;
        __syncthreads();
        sd[t] += x;
        __syncthreads();
    }
    int run = sd[t] - s + blockSums[blockIdx.x];
#pragma unroll
    for (int i = 0; i < 4; ++i) { int idx = base + i; if (idx < KB) offsets[idx] = run; run += c[i]; }
}

// ---------------------------------------------------------------------------
// 3) Scatter src into (dst,rel)-sorted order.
//    Destroys offsets: afterwards offsets[key] == end of bucket.
// ---------------------------------------------------------------------------
__global__ __launch_bounds__(256) void scatter_fill_kernel(
    const int* __restrict__ esrc, const int* __restrict__ edst,
    const int* __restrict__ erel, int* __restrict__ offsets,
    int* __restrict__ sorted, int E)
{
    int i = blockIdx.x * 256 + threadIdx.x;
    const int stride = gridDim.x * 256;
    for (; i < E; i += stride) {
        const int pos = atomicAdd(&offsets[edst[i] * 8 + erel[i]], 1);
        sorted[pos] = esrc[i];
    }
}

// ---------------------------------------------------------------------------
// 4) Cast X -> Xb (bf16, for gathers + self segment) and [W;W0]^T -> Bt.
// ---------------------------------------------------------------------------
__global__ __launch_bounds__(256) void cast_kernel(
    const float* __restrict__ X, const float* __restrict__ W,
    const float* __restrict__ W0, unsigned short* __restrict__ Xb,
    unsigned short* __restrict__ Bt, int M, int R)
{
    const int ktot = (R + 1) * 128;
    const int nx = M * 32;                 // float4 chunks of X
    const int idx = blockIdx.x * 256 + threadIdx.x;
    if (idx < nx) {
        const float4 v = ((const float4*)X)[idx];
        uint2 p;
        p.x = (unsigned)f2bf(v.x) | ((unsigned)f2bf(v.y) << 16);
        p.y = (unsigned)f2bf(v.z) | ((unsigned)f2bf(v.w) << 16);
        *(uint2*)(Xb + (size_t)idx * 4) = p;
    } else if (idx < nx + 128 * ktot) {
        const int e = idx - nx;
        const int n = e / ktot;
        const int k = e - n * ktot;
        const float v = (k < R * 128) ? W[(size_t)k * 128 + n]
                                      : W0[(size_t)(k - R * 128) * 128 + n];
        Bt[(size_t)n * ktot + k] = f2bf(v);
    }
}

// ---------------------------------------------------------------------------
// 5) dst-major aggregate, one wave per dst, gathering from bf16 Xb
//    (4 B/lane per edge row instead of 8). r is a compile-time unrolled
//    loop var -> scalar VGPR accumulators, no LDS. srcs broadcast via
//    v_readlane (scalar X-row base).
// ---------------------------------------------------------------------------
__global__ __launch_bounds__(256) void aggregate_kernel(
    const unsigned short* __restrict__ Xb, const float* __restrict__ inv_norm,
    const int* __restrict__ sorted, const int* __restrict__ counts,
    const int* __restrict__ bucket_end, unsigned short* __restrict__ A,
    int N)
{
    const int dst = (int)((blockIdx.x * blockDim.x + threadIdx.x) >> 6);
    if (dst >= N) return;
    const int lane = threadIdx.x & 63;
    const int key0 = dst * 8;

    const int   cnt_l = (lane < 8) ? counts[key0 + lane] : 0;
    const int   end_l = (lane < 8) ? bucket_end[key0 + lane] : 0;
    const float nv_l  = (lane < 8) ? inv_norm[(size_t)lane * N + dst] : 0.f;

    const int bstart = __builtin_amdgcn_readlane(end_l, 0)
                     - __builtin_amdgcn_readlane(cnt_l, 0);
    const int bend   = __builtin_amdgcn_readlane(end_l, 7);
    const int total  = bend - bstart;

    // one coalesced batch covers the whole bucket in the common case
    int batch = 0;
    if (bstart + lane < bend) batch = sorted[bstart + lane];

    unsigned short* Arow = A + (size_t)dst * 1152 + lane * 2;

#pragma unroll
    for (int r = 0; r < 8; ++r) {
        const int cnt = __builtin_amdgcn_readlane(cnt_l, r);
        const int end = __builtin_amdgcn_readlane(end_l, r);
        const int st  = end - cnt;
        float ax = 0.f, ay = 0.f;
        if (total <= 64) {
            const int base = st - bstart;
            int j = 0;
            for (; j + 4 <= cnt; j += 4) {
                const int s0 = __builtin_amdgcn_readlane(batch, base + j);
                const int s1 = __builtin_amdgcn_readlane(batch, base + j + 1);
                const int s2 = __builtin_amdgcn_readlane(batch, base + j + 2);
                const int s3 = __builtin_amdgcn_readlane(batch, base + j + 3);
                const unsigned u0 = ((const unsigned*)(Xb + ((size_t)s0 << 7)))[lane];
                const unsigned u1 = ((const unsigned*)(Xb + ((size_t)s1 << 7)))[lane];
                const unsigned u2 = ((const unsigned*)(Xb + ((size_t)s2 << 7)))[lane];
                const unsigned u3 = ((const unsigned*)(Xb + ((size_t)s3 << 7)))[lane];
                ax += bflo(u0); ay += bfhi(u0);
                ax += bflo(u1); ay += bfhi(u1);
                ax += bflo(u2); ay += bfhi(u2);
                ax += bflo(u3); ay += bfhi(u3);
            }
            for (; j < cnt; ++j) {
                const int s0 = __builtin_amdgcn_readlane(batch, base + j);
                const unsigned u = ((const unsigned*)(Xb + ((size_t)s0 << 7)))[lane];
                ax += bflo(u); ay += bfhi(u);
            }
        } else {
            // rare (degree>64): uniform per-edge loads
            int i = st;
            for (; i + 2 <= end; i += 2) {
                const int s0 = sorted[i], s1 = sorted[i + 1];
                const unsigned u0 = ((const unsigned*)(Xb + ((size_t)s0 << 7)))[lane];
                const unsigned u1 = ((const unsigned*)(Xb + ((size_t)s1 << 7)))[lane];
                ax += bflo(u0); ay += bfhi(u0);
                ax += bflo(u1); ay += bfhi(u1);
            }
            for (; i < end; ++i) {
                const int s0 = sorted[i];
                const unsigned u = ((const unsigned*)(Xb + ((size_t)s0 << 7)))[lane];
                ax += bflo(u); ay += bfhi(u);
            }
        }
        const float s = readlane_f(nv_l, r);
        const unsigned packed = (unsigned)f2bf(ax * s)
                              | ((unsigned)f2bf(ay * s) << 16);
        *(unsigned*)(Arow + r * 128) = packed;
    }
    // self segment: bf16(X[dst]) straight from Xb
    const unsigned px = ((const unsigned*)(Xb + ((size_t)dst << 7)))[lane];
    *(unsigned*)(Arow + 8 * 128) = px;
}

// ---------------------------------------------------------------------------
// 6) bf16 MFMA GEMM: out[M,128] = A[M,KT] @ Bt[128,KT]^T (fp32 out)
//    512 threads = 8 waves; 64 rows x 128 cols per block; BK=128:
//    one 32.8 KB B-tile staged per outer step (18 barriers total, was 72).
// ---------------------------------------------------------------------------
template <int KT>
__global__ __launch_bounds__(512) void gemm_kernel(
    const unsigned short* __restrict__ A, const unsigned short* __restrict__ Bt,
    float* __restrict__ out, int M)
{
    __shared__ unsigned short Bs[128][136];  // [n][128k]+8 pad; pitch 272B (16B-aligned)
    const int tid = threadIdx.x;
    const int wave = tid >> 6;               // 0..7
    const int lane = tid & 63;
    const int ln = lane & 15, quad = lane >> 4;
    const int mt = wave >> 1;                // 0..3 (16-row tile)
    const int half = wave & 1;               // 0..1 (64-col half)
    const int m0 = blockIdx.x * 64;
    int m = m0 + mt * 16 + ln; if (m >= M) m = M - 1;   // clamp; stores guarded
    const unsigned short* Arow = A + (size_t)m * KT + quad * 8;

    // B staging: thread t stages 64 contiguous bytes: row tid>>2, k-off (tid&3)*32
    const int sn = tid >> 2, sk = (tid & 3) * 32;
    const unsigned short* Bsrc = Bt + (size_t)sn * KT + sk;

    f32x4 acc[4] = {};
#pragma unroll
    for (int ko = 0; ko < KT / 128; ++ko) {
        const short8 st0 = *(const short8*)(Bsrc + ko * 128 + 0);
        const short8 st1 = *(const short8*)(Bsrc + ko * 128 + 8);
        const short8 st2 = *(const short8*)(Bsrc + ko * 128 + 16);
        const short8 st3 = *(const short8*)(Bsrc + ko * 128 + 24);
        __syncthreads();
        *(short8*)&Bs[sn][sk + 0]  = st0;
        *(short8*)&Bs[sn][sk + 8]  = st1;
        *(short8*)&Bs[sn][sk + 16] = st2;
        *(short8*)&Bs[sn][sk + 24] = st3;
        __syncthreads();
#pragma unroll
        for (int ks = 0; ks < 4; ++ks) {
            const short8 a = *(const short8*)(Arow + ko * 128 + ks * 32);
#pragma unroll
            for (int c = 0; c < 4; ++c) {
                const short8 b = *(const short8*)&Bs[half * 64 + c * 16 + ln][ks * 32 + quad * 8];
                acc[c] = __builtin_amdgcn_mfma_f32_16x16x32_bf16(a, b, acc[c], 0, 0, 0);
            }
        }
    }
#pragma unroll
    for (int c = 0; c < 4; ++c) {
#pragma unroll
        for (int rg = 0; rg < 4; ++rg) {
            const int row = m0 + mt * 16 + quad * 4 + rg;
            if (row < M)
                out[(size_t)row * 128 + half * 64 + c * 16 + ln] = acc[c][rg];
        }
    }
}

// Generic-K fallback (runtime loop bound), slow but correct
__global__ __launch_bounds__(256) void gemm_kernel_rt(
    const unsigned short* __restrict__ A, const unsigned short* __restrict__ Bt,
    float* __restrict__ out, int M, int ktot)
{
    const int tid = threadIdx.x;
    const int wave = tid >> 6;
    const int lane = tid & 63;
    const int ln = lane & 15, quad = lane >> 4;
    const int m0 = blockIdx.x * 64 + wave * 16;
    int m = m0 + ln; if (m >= M) m = M - 1;
    const unsigned short* Arow = A + (size_t)m * ktot + quad * 8;
    const unsigned short* Bbase = Bt + (size_t)ln * ktot + quad * 8;

    f32x4 acc[8] = {};
    for (int kb = 0; kb < (ktot >> 5); ++kb) {
        const int k0 = kb << 5;
        const short8 a = *(const short8*)(Arow + k0);
#pragma unroll
        for (int c = 0; c < 8; ++c) {
            const short8 b = *(const short8*)(Bbase + (size_t)c * 16 * ktot + k0);
            acc[c] = __builtin_amdgcn_mfma_f32_16x16x32_bf16(a, b, acc[c], 0, 0, 0);
        }
    }
#pragma unroll
    for (int c = 0; c < 8; ++c) {
#pragma unroll
        for (int rg = 0; rg < 4; ++rg) {
            const int row = m0 + quad * 4 + rg;
            if (row < M) out[(size_t)row * 128 + c * 16 + ln] = acc[c][rg];
        }
    }
}

// ---------------------------------------------------------------------------
extern "C" void kernel_launch(void* const* d_in, const int* in_sizes, int n_in,
                              void* d_out, int out_size, void* d_ws, size_t ws_size,
                              hipStream_t stream) {
    const float* X        = (const float*)d_in[0];
    const float* W        = (const float*)d_in[1];
    const float* W0       = (const float*)d_in[2];
    const float* inv_norm = (const float*)d_in[3];
    const int*   esrc     = (const int*)d_in[4];
    const int*   edst     = (const int*)d_in[5];
    const int*   erel     = (const int*)d_in[6];
    float* out = (float*)d_out;

    const int N  = in_sizes[0] / 128;     // 50000
    const int E  = in_sizes[4];           // 800000
    const int R  = in_sizes[3] / N;       // 8
    const int KB = N * 8;                 // 400000 (dst-major keys)
    const int ktot = (R + 1) * 128;       // 1152

    char* ws = (char*)d_ws;
    size_t off = 0;
    auto alloc = [&](size_t bytes) -> char* {
        char* p = ws + off; off = (off + bytes + 255) & ~(size_t)255; return p;
    };
    unsigned short* A         = (unsigned short*)alloc((size_t)N * ktot * 2);   // 115.2 MB
    unsigned short* Xb        = (unsigned short*)alloc((size_t)N * 128 * 2);    // 12.8 MB
    unsigned short* Bt        = (unsigned short*)alloc((size_t)128 * ktot * 2); // 0.3 MB
    int*            counts    = (int*)alloc((size_t)KB * 4);                    // 1.6 MB
    int*            offsets   = (int*)alloc((size_t)KB * 4);                    // 1.6 MB
    int*            blockSums = (int*)alloc(512 * 4);
    int*            sorted    = (int*)alloc((size_t)E * 4);                     // 3.2 MB
    (void)ws_size;

    const int nScanBlocks = (KB + 1023) / 1024;   // 391 (<=512)

    hipMemsetAsync(counts, 0, (size_t)KB * 4, stream);
    hist_kernel<<<1024, 256, 0, stream>>>(edst, erel, counts, E);
    scan1_kernel<<<nScanBlocks, 256, 0, stream>>>(counts, blockSums, KB);
    scan2_kernel<<<1, 512, 0, stream>>>(blockSums, nScanBlocks);
    scan3_kernel<<<nScanBlocks, 256, 0, stream>>>(counts, blockSums, offsets, KB);
    scatter_fill_kernel<<<1024, 256, 0, stream>>>(esrc, edst, erel, offsets, sorted, E);
    cast_kernel<<<(N * 32 + 128 * ktot + 255) / 256, 256, 0, stream>>>(X, W, W0, Xb, Bt, N, R);
    aggregate_kernel<<<(N + 3) / 4, 256, 0, stream>>>(Xb, inv_norm, sorted, counts, offsets, A, N);
    if (ktot == 1152)
        gemm_kernel<1152><<<(N + 63) / 64, 512, 0, stream>>>(A, Bt, out, N);
    else
        gemm_kernel_rt<<<(N + 63) / 64, 256, 0, stream>>>(A, Bt, out, N, ktot);
}